// Round 1
// baseline (3766.913 us; speedup 1.0000x reference)
//
#include <hip/hip_runtime.h>
#include <stdint.h>

#define NWG_REC 64

typedef __bf16 bf16x8 __attribute__((ext_vector_type(8)));
typedef float  f32x4  __attribute__((ext_vector_type(4)));

typedef __attribute__((address_space(1))) void as1_void;
typedef __attribute__((address_space(3))) void as3_void;

__device__ __forceinline__ f32x4 mfma16(bf16x8 a, bf16x8 b, f32x4 c) {
  return __builtin_amdgcn_mfma_f32_16x16x32_bf16(a, b, c, 0, 0, 0);
}

__device__ __forceinline__ void gload_lds16(const void* g, void* l) {
  __builtin_amdgcn_global_load_lds((as1_void*)g, (as3_void*)l, 16, 0, 0);
}

// ---------------- transpose f32[R][C] -> bf16 out[C][R] (out ptr may be offset; stride R)
__global__ __launch_bounds__(256) void k_transpose(const float* __restrict__ in,
                                                   __bf16* __restrict__ out,
                                                   int R, int C) {
  __shared__ float tile[64][65];
  int c0 = blockIdx.x * 64, r0 = blockIdx.y * 64;
  int lane = threadIdx.x & 63, grp = threadIdx.x >> 6;
  for (int i = grp; i < 64; i += 4)
    tile[i][lane] = in[(size_t)(r0 + i) * C + (c0 + lane)];
  __syncthreads();
  for (int i = grp; i < 64; i += 4)
    out[(size_t)(c0 + i) * R + (r0 + lane)] = (__bf16)tile[lane][i];
}

// ---------------- X = shift(masked target) -> bf16 [4096][512]
__global__ void k_make_x(const float* __restrict__ target, const int* __restrict__ mask,
                         __bf16* __restrict__ X) {
  int e4 = blockIdx.x * 256 + threadIdx.x;   // 524288 float4s
  int m = e4 >> 7, d4 = e4 & 127;
  int t = m & 127, b = m >> 7;
  float4 v = make_float4(0.f, 0.f, 0.f, 0.f);
  if (t > 0) {
    float mf = (float)mask[b * 128 + t - 1];
    v = reinterpret_cast<const float4*>(target + (size_t)(b * 128 + t - 1) * 512)[d4];
    v.x *= mf; v.y *= mf; v.z *= mf; v.w *= mf;
  }
  __bf16* o = X + (size_t)m * 512 + d4 * 4;
  o[0] = (__bf16)v.x; o[1] = (__bf16)v.y; o[2] = (__bf16)v.z; o[3] = (__bf16)v.w;
}

// ---------------- context -> bf16 padded [128][512]
__global__ void k_make_ctx(const float* __restrict__ ctx, __bf16* __restrict__ out) {
  int i = blockIdx.x * 256 + threadIdx.x;    // 65536
  float v = (i < 32 * 512) ? ctx[i] : 0.f;
  out[i] = (__bf16)v;
}

// ---------------- TN bf16 MFMA GEMM: C[M][N] = A[M][K] @ B[N][K]^T + bias2d[m>>7][n]
__global__ __launch_bounds__(256) void k_gemm(const __bf16* __restrict__ A,
                                              const __bf16* __restrict__ B,
                                              const float* __restrict__ bias2d,
                                              float* __restrict__ C,
                                              int N, int K) {
  __shared__ __align__(16) __bf16 lA[128 * 64];
  __shared__ __align__(16) __bf16 lB[128 * 64];
  int tot = gridDim.x * gridDim.y;
  int id = blockIdx.y * gridDim.x + blockIdx.x;
  int q = tot >> 3, rr = tot & 7;
  int xcd = id & 7, pos = id >> 3;
  int swz = (xcd < rr ? xcd * (q + 1) : rr * (q + 1) + (xcd - rr) * q) + pos;
  int bx = swz % gridDim.x, by = swz / gridDim.x;
  int m0 = by * 128, n0 = bx * 128;
  int tid = threadIdx.x, w = tid >> 6, l = tid & 63;
  int wm = w >> 1, wn = w & 1;
  int kb0 = (l & 7) * 16;
  f32x4 acc[4][4] = {};
  for (int kt = 0; kt < K; kt += 64) {
    __syncthreads();
#pragma unroll
    for (int r = 0; r < 4; ++r) {
      int seg = w * 4 + r;
      int row = seg * 8 + (l >> 3);
      int kbg = kb0 ^ ((row & 7) << 4);
      gload_lds16((const char*)(A + (size_t)(m0 + row) * K + kt) + kbg, (char*)lA + seg * 1024);
      gload_lds16((const char*)(B + (size_t)(n0 + row) * K + kt) + kbg, (char*)lB + seg * 1024);
    }
    __syncthreads();
#pragma unroll
    for (int kk = 0; kk < 2; ++kk) {
      bf16x8 af[4], bfr[4];
#pragma unroll
      for (int i = 0; i < 4; ++i) {
        int arow = wm * 64 + i * 16 + (l & 15);
        af[i] = *reinterpret_cast<const bf16x8*>(
            (const char*)lA + arow * 128 + ((kk * 64 + (l >> 4) * 16) ^ ((arow & 7) << 4)));
        int brow = wn * 64 + i * 16 + (l & 15);
        bfr[i] = *reinterpret_cast<const bf16x8*>(
            (const char*)lB + brow * 128 + ((kk * 64 + (l >> 4) * 16) ^ ((brow & 7) << 4)));
      }
#pragma unroll
      for (int i = 0; i < 4; ++i)
#pragma unroll
        for (int j = 0; j < 4; ++j)
          acc[i][j] = mfma16(af[i], bfr[j], acc[i][j]);
    }
  }
#pragma unroll
  for (int i = 0; i < 4; ++i) {
    int rb = m0 + wm * 64 + i * 16 + ((l >> 4) << 2);
#pragma unroll
    for (int j = 0; j < 4; ++j) {
      int col = n0 + wn * 64 + j * 16 + (l & 15);
#pragma unroll
      for (int e = 0; e < 4; ++e) {
        int row = rb + e;
        C[(size_t)row * N + col] = acc[i][j][e] + bias2d[(size_t)(row >> 7) * N + col];
      }
    }
  }
}

// ---------------- global barrier (one counter per instance, pre-zeroed)
__device__ __forceinline__ void gbar(int* c) {
  __syncthreads();
  if (threadIdx.x == 0) {
    __threadfence();
    atomicAdd(c, 1);
    while (__hip_atomic_load(c, __ATOMIC_ACQUIRE, __HIP_MEMORY_SCOPE_AGENT) < NWG_REC)
      __builtin_amdgcn_s_sleep(1);
  }
  __syncthreads();
}

// ---------------- GRU recurrence: 64 WGs, WG g owns h-columns [16g,16g+16)
__global__ __launch_bounds__(256) void k_recurrence(
    const float* __restrict__ xzrh,      // [4096][3072] (z|r|h)
    const __bf16* __restrict__ Ut,       // [3][1024][1024] transposed (Ut[j][k]=U[k][j])
    const int* __restrict__ mask,        // [32][128]
    __bf16* __restrict__ hm_buf,         // [32][1024] pre-zeroed
    __bf16* __restrict__ q_buf,          // [32][1024]
    __bf16* __restrict__ h_seq,          // [4096][1024]
    int* __restrict__ cnt) {             // [256] pre-zeroed
  __shared__ __align__(16) __bf16 s_vec[32 * 1024];   // 64KB, swizzled
  __shared__ float s_part[2][4][32][16];
  __shared__ float s_z[32][16];
  __shared__ float s_hm[32][16];
  int g = blockIdx.x, tid = threadIdx.x, w = tid >> 6, l = tid & 63;
  int jg0 = g * 16;
  const __bf16* Uz = Ut;
  const __bf16* Ur = Ut + 1024 * 1024;
  const __bf16* Uh = Ut + 2 * 1024 * 1024;

  auto stage = [&](const __bf16* src) {
#pragma unroll
    for (int i = 0; i < 16; ++i) {
      int L = tid * 16 + i * 4096;
      int b = L >> 11, kb = L & 2047;
      uint4 v = *reinterpret_cast<const uint4*>(reinterpret_cast<const char*>(src) + L);
      *reinterpret_cast<uint4*>(reinterpret_cast<char*>(s_vec) + b * 2048 + (kb ^ ((b & 7) << 4))) = v;
    }
  };

  for (int t = 0; t < 128; ++t) {
    // -------- phase A: z, r, q = r*hm --------
    stage(hm_buf);
    __syncthreads();
    f32x4 az[2] = {}, ar[2] = {};
#pragma unroll
    for (int ks = 0; ks < 8; ++ks) {
      int k = w * 256 + ks * 32 + ((l >> 4) << 3);
      size_t uoff = (size_t)(jg0 + (l & 15)) * 1024 + k;
      bf16x8 bz = *reinterpret_cast<const bf16x8*>(Uz + uoff);
      bf16x8 br = *reinterpret_cast<const bf16x8*>(Ur + uoff);
#pragma unroll
      for (int mt = 0; mt < 2; ++mt) {
        int b = mt * 16 + (l & 15);
        bf16x8 a = *reinterpret_cast<const bf16x8*>(
            reinterpret_cast<const char*>(s_vec) + b * 2048 + ((k * 2) ^ ((b & 7) << 4)));
        az[mt] = mfma16(a, bz, az[mt]);
        ar[mt] = mfma16(a, br, ar[mt]);
      }
    }
#pragma unroll
    for (int mt = 0; mt < 2; ++mt)
#pragma unroll
      for (int e = 0; e < 4; ++e) {
        int b = mt * 16 + ((l >> 4) << 2) + e;
        s_part[0][w][b][l & 15] = az[mt][e];
        s_part[1][w][b][l & 15] = ar[mt][e];
      }
    __syncthreads();
    for (int p = tid; p < 512; p += 256) {
      int b = p >> 4, j = p & 15;
      float sz = s_part[0][0][b][j] + s_part[0][1][b][j] + s_part[0][2][b][j] + s_part[0][3][b][j];
      float sr = s_part[1][0][b][j] + s_part[1][1][b][j] + s_part[1][2][b][j] + s_part[1][3][b][j];
      size_t m = (size_t)b * 128 + t;
      float xz = xzrh[m * 3072 + jg0 + j];
      float xr = xzrh[m * 3072 + 1024 + jg0 + j];
      float z = 1.f / (1.f + __expf(-(xz + sz)));
      float r = 1.f / (1.f + __expf(-(xr + sr)));
      int kj = jg0 + j;
      float hmv = (float)*reinterpret_cast<const __bf16*>(
          reinterpret_cast<const char*>(s_vec) + b * 2048 + ((kj * 2) ^ ((b & 7) << 4)));
      s_z[b][j] = z;
      s_hm[b][j] = hmv;
      q_buf[b * 1024 + kj] = (__bf16)(r * hmv);
    }
    gbar(cnt + 2 * t);
    // -------- phase B: hh, h update --------
    stage(q_buf);
    __syncthreads();
    f32x4 ah[2] = {};
#pragma unroll
    for (int ks = 0; ks < 8; ++ks) {
      int k = w * 256 + ks * 32 + ((l >> 4) << 3);
      size_t uoff = (size_t)(jg0 + (l & 15)) * 1024 + k;
      bf16x8 bh = *reinterpret_cast<const bf16x8*>(Uh + uoff);
#pragma unroll
      for (int mt = 0; mt < 2; ++mt) {
        int b = mt * 16 + (l & 15);
        bf16x8 a = *reinterpret_cast<const bf16x8*>(
            reinterpret_cast<const char*>(s_vec) + b * 2048 + ((k * 2) ^ ((b & 7) << 4)));
        ah[mt] = mfma16(a, bh, ah[mt]);
      }
    }
#pragma unroll
    for (int mt = 0; mt < 2; ++mt)
#pragma unroll
      for (int e = 0; e < 4; ++e) {
        int b = mt * 16 + ((l >> 4) << 2) + e;
        s_part[0][w][b][l & 15] = ah[mt][e];
      }
    __syncthreads();
    for (int p = tid; p < 512; p += 256) {
      int b = p >> 4, j = p & 15;
      float sh = s_part[0][0][b][j] + s_part[0][1][b][j] + s_part[0][2][b][j] + s_part[0][3][b][j];
      size_t m = (size_t)b * 128 + t;
      float xh = xzrh[m * 3072 + 2048 + jg0 + j];
      float hh = tanhf(xh + sh);
      float z = s_z[b][j], hmv = s_hm[b][j];
      float h = z * hmv + (1.f - z) * hh;
      int kj = jg0 + j;
      h_seq[m * 1024 + kj] = (__bf16)h;
      float mf = (float)mask[b * 128 + t];
      hm_buf[b * 1024 + kj] = (__bf16)(mf * h);
    }
    if (t != 127) gbar(cnt + 2 * t + 1);
  }
}

// ---------------- row softmax in place, one block per row of 32000
__global__ __launch_bounds__(256) void k_softmax(float* __restrict__ out) {
  float* p = out + (size_t)blockIdx.x * 32000;
  int tid = threadIdx.x;
  float m = -1e30f, s = 0.f;
  for (int i = tid; i < 8000; i += 256) {
    float4 v = reinterpret_cast<const float4*>(p)[i];
    float mv = fmaxf(fmaxf(v.x, v.y), fmaxf(v.z, v.w));
    if (mv > m) { s *= __expf(m - mv); m = mv; }
    s += __expf(v.x - m) + __expf(v.y - m) + __expf(v.z - m) + __expf(v.w - m);
  }
#pragma unroll
  for (int off = 32; off; off >>= 1) {
    float mo = __shfl_down(m, off);
    float so = __shfl_down(s, off);
    float M = fmaxf(m, mo);
    s = s * __expf(m - M) + so * __expf(mo - M);
    m = M;
  }
  __shared__ float sm[4], ss[4];
  if ((tid & 63) == 0) { sm[tid >> 6] = m; ss[tid >> 6] = s; }
  __syncthreads();
  float M = fmaxf(fmaxf(sm[0], sm[1]), fmaxf(sm[2], sm[3]));
  float S = ss[0] * __expf(sm[0] - M) + ss[1] * __expf(sm[1] - M) +
            ss[2] * __expf(sm[2] - M) + ss[3] * __expf(sm[3] - M);
  float rinv = 1.f / S;
  for (int i = tid; i < 8000; i += 256) {
    float4 v = reinterpret_cast<const float4*>(p)[i];
    v.x = __expf(v.x - M) * rinv; v.y = __expf(v.y - M) * rinv;
    v.z = __expf(v.z - M) * rinv; v.w = __expf(v.w - M) * rinv;
    reinterpret_cast<float4*>(p)[i] = v;
  }
}

extern "C" void kernel_launch(void* const* d_in, const int* in_sizes, int n_in,
                              void* d_out, int out_size, void* d_ws, size_t ws_size,
                              hipStream_t stream) {
  (void)in_sizes; (void)n_in; (void)out_size; (void)ws_size;
  const float* target  = (const float*)d_in[0];
  const float* context = (const float*)d_in[1];
  const int*   mask    = (const int*)d_in[2];
  const float* W_z = (const float*)d_in[3];
  const float* U_z = (const float*)d_in[4];
  const float* C_z = (const float*)d_in[5];
  const float* b_z = (const float*)d_in[6];
  const float* W_r = (const float*)d_in[7];
  const float* U_r = (const float*)d_in[8];
  const float* C_r = (const float*)d_in[9];
  const float* b_r = (const float*)d_in[10];
  const float* W_h = (const float*)d_in[11];
  const float* U_h = (const float*)d_in[12];
  const float* C_h = (const float*)d_in[13];
  const float* b_h = (const float*)d_in[14];
  const float* U_y = (const float*)d_in[15];
  const float* C_y = (const float*)d_in[16];
  const float* b_y = (const float*)d_in[17];

  char* ws = (char*)d_ws;
  size_t off = 0;
  auto alloc = [&](size_t b) { char* p = ws + off; off += (b + 255) & ~(size_t)255; return p; };
  int*    cnt     = (int*)   alloc(1024);
  __bf16* hm_buf  = (__bf16*)alloc(65536);
  __bf16* q_buf   = (__bf16*)alloc(65536);
  __bf16* UyT     = (__bf16*)alloc((size_t)32000 * 1024 * 2);
  __bf16* UtZRH   = (__bf16*)alloc((size_t)3 * 1024 * 1024 * 2);
  __bf16* WcatT   = (__bf16*)alloc((size_t)3072 * 512 * 2);
  __bf16* CyT     = (__bf16*)alloc((size_t)32000 * 512 * 2);
  __bf16* CzrhT   = (__bf16*)alloc((size_t)3072 * 512 * 2);
  __bf16* Xb      = (__bf16*)alloc((size_t)4096 * 512 * 2);
  __bf16* ctxb    = (__bf16*)alloc((size_t)128 * 512 * 2);
  float*  biaszrh = (float*) alloc((size_t)3072 * 4);
  float*  xzrh    = (float*) alloc((size_t)4096 * 3072 * 4);
  float*  czrh    = (float*) alloc((size_t)128 * 3072 * 4);
  float*  cyctx   = (float*) alloc((size_t)128 * 32000 * 4);
  __bf16* hseq    = (__bf16*)alloc((size_t)4096 * 1024 * 2);

  hipMemsetAsync(d_ws, 0, 132096, stream);   // cnt + hm_buf + q_buf

  dim3 blk(256);
  // weight transposes/conversions (bf16, [N][K] layout)
  k_transpose<<<dim3(500, 16), blk, 0, stream>>>(U_y, UyT, 1024, 32000);
  k_transpose<<<dim3(16, 16), blk, 0, stream>>>(U_z, UtZRH, 1024, 1024);
  k_transpose<<<dim3(16, 16), blk, 0, stream>>>(U_r, UtZRH + 1024 * 1024, 1024, 1024);
  k_transpose<<<dim3(16, 16), blk, 0, stream>>>(U_h, UtZRH + 2 * 1024 * 1024, 1024, 1024);
  k_transpose<<<dim3(16, 8), blk, 0, stream>>>(W_z, WcatT, 512, 1024);
  k_transpose<<<dim3(16, 8), blk, 0, stream>>>(W_r, WcatT + 1024 * 512, 512, 1024);
  k_transpose<<<dim3(16, 8), blk, 0, stream>>>(W_h, WcatT + 2048 * 512, 512, 1024);
  k_transpose<<<dim3(500, 8), blk, 0, stream>>>(C_y, CyT, 512, 32000);
  k_transpose<<<dim3(16, 8), blk, 0, stream>>>(C_z, CzrhT, 512, 1024);
  k_transpose<<<dim3(16, 8), blk, 0, stream>>>(C_r, CzrhT + 1024 * 512, 512, 1024);
  k_transpose<<<dim3(16, 8), blk, 0, stream>>>(C_h, CzrhT + 2048 * 512, 512, 1024);
  // activations prep
  k_make_x<<<dim3(2048), blk, 0, stream>>>(target, mask, Xb);
  k_make_ctx<<<dim3(256), blk, 0, stream>>>(context, ctxb);
  hipMemcpyAsync(biaszrh,        b_z, 4096, hipMemcpyDeviceToDevice, stream);
  hipMemcpyAsync(biaszrh + 1024, b_r, 4096, hipMemcpyDeviceToDevice, stream);
  hipMemcpyAsync(biaszrh + 2048, b_h, 4096, hipMemcpyDeviceToDevice, stream);
  // context projections (M padded to 128; bias row 0)
  k_gemm<<<dim3(24, 1), blk, 0, stream>>>(ctxb, CzrhT, biaszrh, czrh, 3072, 512);
  k_gemm<<<dim3(250, 1), blk, 0, stream>>>(ctxb, CyT, b_y, cyctx, 32000, 512);
  // input projections: xzrh = X@Wcat + czrh[b]
  k_gemm<<<dim3(24, 32), blk, 0, stream>>>(Xb, WcatT, czrh, xzrh, 3072, 512);
  // sequential GRU scan
  k_recurrence<<<dim3(64), blk, 0, stream>>>(xzrh, UtZRH, mask, hm_buf, q_buf, hseq, cnt);
  // output projection -> logits in d_out
  k_gemm<<<dim3(250, 32), blk, 0, stream>>>(hseq, UyT, cyctx, (float*)d_out, 32000, 1024);
  // softmax in place
  k_softmax<<<dim3(4096), blk, 0, stream>>>((float*)d_out);
}